// Round 1
// baseline (1083.956 us; speedup 1.0000x reference)
//
#include <hip/hip_runtime.h>
#include <hip/hip_bf16.h>

#define GRID_ELEMS (8*64*64*64)   // 2,097,152 voxels at level 0
#define H2_VOX     (8*32*32*32)   // 262,144 voxels at level 2
#define H3_VOX     (8*16*16*16)   // 32,768 voxels at level 3

// ---------------------------------------------------------------- scatter
__global__ __launch_bounds__(256) void scatter_k(
    const int* __restrict__ coords, const float* __restrict__ feats,
    float* __restrict__ grid, float* __restrict__ mask, int N)
{
  int i = blockIdx.x * 256 + threadIdx.x;
  if (i >= N) return;
  const int4 c = reinterpret_cast<const int4*>(coords)[i];
  int idx = ((c.x * 64 + c.y) * 64 + c.z) * 64 + c.w;   // b,x,y,z
  atomicAdd(&grid[idx], feats[i]);
  mask[idx] = 1.0f;   // racy same-value store: benign
}

// ------------------------------------------- conv1+relu*mask+conv2+relu*mask2
// One thread per level-2 output voxel; computes all 64 channels.
// h1 (level-1) is non-overlapping w.r.t. conv2 (kernel2/stride2), so each
// h1 voxel is computed exactly once, in registers.
__global__ __launch_bounds__(256) void fused12_k(
    const float* __restrict__ grid, const float* __restrict__ mask,
    const float* __restrict__ W1, const float* __restrict__ W2,
    float* __restrict__ h2, float* __restrict__ m2out)
{
  __shared__ float W1s[27 * 32];       // 3.4 KB
  __shared__ float W2s[8 * 32 * 64];   // 64 KB
  const int tid = threadIdx.x;
  for (int i = tid; i < 27 * 32; i += 256) W1s[i] = W1[i];
  for (int i = tid; i < 4096; i += 256)
    reinterpret_cast<float4*>(W2s)[i] = reinterpret_cast<const float4*>(W2)[i];
  __syncthreads();

  const int v  = blockIdx.x * 256 + tid;     // [0, 262144)
  const int b  = v >> 15;
  const int x2 = (v >> 10) & 31, y2 = (v >> 5) & 31, z2 = v & 31;
  const int gb = b << 18;                    // b * 64^3

  float acc[64];
  #pragma unroll
  for (int o = 0; o < 64; ++o) acc[o] = 0.f;
  float m2v = 0.f;

  #pragma unroll 1
  for (int p = 0; p < 8; ++p) {
    const int x1 = 2 * x2 + (p >> 2);
    const int y1 = 2 * y2 + ((p >> 1) & 1);
    const int z1 = 2 * z2 + (p & 1);
    const float mk = mask[gb + (x1 << 12) + (y1 << 6) + z1];
    m2v = fmaxf(m2v, mk);

    // conv1 at (x1,y1,z1): 27 taps, 32 channels
    float h1[32];
    #pragma unroll
    for (int c = 0; c < 32; ++c) h1[c] = 0.f;
    #pragma unroll
    for (int tx = 0; tx < 3; ++tx) {
      const int gx = x1 + tx - 1;
      #pragma unroll
      for (int ty = 0; ty < 3; ++ty) {
        const int gy = y1 + ty - 1;
        #pragma unroll
        for (int tz = 0; tz < 3; ++tz) {
          const int gz = z1 + tz - 1;
          const bool ok = ((unsigned)gx < 64u) & ((unsigned)gy < 64u) & ((unsigned)gz < 64u);
          const float g = ok ? grid[gb + (gx << 12) + (gy << 6) + gz] : 0.f;
          const float* w = &W1s[((tx * 3 + ty) * 3 + tz) * 32];
          #pragma unroll
          for (int c = 0; c < 32; ++c) h1[c] = fmaf(g, w[c], h1[c]);
        }
      }
    }

    // relu*mask, then conv2 accumulate into 64 output channels
    const float* w2p = &W2s[p * 2048];
    #pragma unroll
    for (int c = 0; c < 32; ++c) {
      const float hv = fmaxf(h1[c], 0.f) * mk;
      const float* w = &w2p[c * 64];
      #pragma unroll
      for (int o = 0; o < 64; ++o) acc[o] = fmaf(hv, w[o], acc[o]);
    }
  }

  // h2 = relu(conv2) * mask2
  float4* hp = reinterpret_cast<float4*>(h2 + ((size_t)v << 6));
  #pragma unroll
  for (int o4 = 0; o4 < 16; ++o4) {
    float4 t;
    t.x = fmaxf(acc[o4 * 4 + 0], 0.f) * m2v;
    t.y = fmaxf(acc[o4 * 4 + 1], 0.f) * m2v;
    t.z = fmaxf(acc[o4 * 4 + 2], 0.f) * m2v;
    t.w = fmaxf(acc[o4 * 4 + 3], 0.f) * m2v;
    hp[o4] = t;
  }
  m2out[v] = m2v;
}

// ------------------------------------- conv3+relu*mask3 + masked global sum
// grid = 128 voxel-groups * 4 channel-chunks. One thread per level-3 voxel,
// 32 output channels per chunk. h3 never materialized: block-reduce -> atomic.
__global__ __launch_bounds__(256) void conv3pool_k(
    const float* __restrict__ h2, const float* __restrict__ m2,
    const float* __restrict__ W3, float* __restrict__ s, float* __restrict__ cnt)
{
  __shared__ float W3s[8 * 64 * 32];   // 64 KB; reused as reduce buffer
  const int tid   = threadIdx.x;
  const int g     = blockIdx.x >> 2;
  const int chunk = blockIdx.x & 3;

  // load W3[:, :, chunk*32 : chunk*32+32]
  for (int i = tid; i < 8 * 64 * 8; i += 256) {   // float4 granules
    const int pc = i >> 3, o4 = i & 7;
    reinterpret_cast<float4*>(W3s)[i] =
        *reinterpret_cast<const float4*>(&W3[pc * 128 + chunk * 32 + o4 * 4]);
  }
  __syncthreads();

  const int v  = g * 256 + tid;              // [0, 32768)
  const int b  = v >> 12;
  const int x3 = (v >> 8) & 15, y3 = (v >> 4) & 15, z3 = v & 15;
  const int hb = b << 15;

  float acc[32];
  #pragma unroll
  for (int o = 0; o < 32; ++o) acc[o] = 0.f;
  float m3 = 0.f;

  #pragma unroll 1
  for (int p = 0; p < 8; ++p) {
    const int x = 2 * x3 + (p >> 2);
    const int y = 2 * y3 + ((p >> 1) & 1);
    const int z = 2 * z3 + (p & 1);
    const int hv = hb + (x << 10) + (y << 5) + z;
    m3 = fmaxf(m3, m2[hv]);
    const float4* hp4 = reinterpret_cast<const float4*>(h2 + ((size_t)hv << 6));
    const float* wp = &W3s[p * 2048];
    #pragma unroll 2
    for (int c4 = 0; c4 < 16; ++c4) {
      const float4 h4 = hp4[c4];
      const float hv4[4] = {h4.x, h4.y, h4.z, h4.w};
      #pragma unroll
      for (int q = 0; q < 4; ++q) {
        const float* w = &W3s[p * 2048 + (c4 * 4 + q) * 32];
        #pragma unroll
        for (int o = 0; o < 32; ++o) acc[o] = fmaf(hv4[q], w[o], acc[o]);
      }
    }
    (void)wp;
  }

  #pragma unroll
  for (int o = 0; o < 32; ++o) acc[o] = fmaxf(acc[o], 0.f) * m3;

  // block reduce (reuse W3s; 256*33 floats = 33.8 KB)
  __syncthreads();
  float* red = W3s;
  #pragma unroll
  for (int o = 0; o < 32; ++o) red[tid * 33 + o] = acc[o];
  red[tid * 33 + 32] = m3;
  __syncthreads();
  if (tid < 33) {
    float sum = 0.f;
    for (int i = 0; i < 256; ++i) sum += red[i * 33 + tid];
    if (tid < 32)            atomicAdd(&s[b * 128 + chunk * 32 + tid], sum);
    else if (chunk == 0)     atomicAdd(&cnt[b], sum);
  }
}

// ---------------------------------------------------------------- final FC
__global__ __launch_bounds__(256) void fc_k(
    const float* __restrict__ s, const float* __restrict__ cnt,
    const float* __restrict__ fc_w, const float* __restrict__ fc_b,
    float* __restrict__ out)
{
  const int b = blockIdx.x, j = threadIdx.x;
  const float inv = 1.f / fmaxf(cnt[b], 1.f);
  float a = fc_b[j];
  #pragma unroll 8
  for (int c = 0; c < 128; ++c) a = fmaf(s[b * 128 + c] * inv, fc_w[c * 256 + j], a);
  out[b * 256 + j] = a;
}

// ---------------------------------------------------------------- launch
extern "C" void kernel_launch(void* const* d_in, const int* in_sizes, int n_in,
                              void* d_out, int out_size, void* d_ws, size_t ws_size,
                              hipStream_t stream)
{
  const int*   coords = (const int*)  d_in[0];
  const float* feats  = (const float*)d_in[1];
  const float* W1     = (const float*)d_in[2];
  const float* W2     = (const float*)d_in[3];
  const float* W3     = (const float*)d_in[4];
  const float* fc_w   = (const float*)d_in[5];
  const float* fc_b   = (const float*)d_in[6];
  float* out = (float*)d_out;
  const int N = in_sizes[0] / 4;

  float* grid = (float*)d_ws;                       //  8.39 MB
  float* mask = grid + GRID_ELEMS;                  //  8.39 MB
  float* h2   = mask + GRID_ELEMS;                  // 67.1  MB
  float* m2   = h2 + (size_t)H2_VOX * 64;           //  1.05 MB
  float* s    = m2 + H2_VOX;                        //  4 KB
  float* cnt  = s + 1024;                           //  32 B
  // total ws use: ~85 MB

  hipMemsetAsync(grid, 0, (size_t)GRID_ELEMS * 2 * sizeof(float), stream);
  hipMemsetAsync(s,    0, (1024 + 8) * sizeof(float), stream);

  scatter_k  <<<(N + 255) / 256, 256, 0, stream>>>(coords, feats, grid, mask, N);
  fused12_k  <<<H2_VOX / 256,    256, 0, stream>>>(grid, mask, W1, W2, h2, m2);
  conv3pool_k<<<(H3_VOX / 256)*4,256, 0, stream>>>(h2, m2, W3, s, cnt);
  fc_k       <<<8,               256, 0, stream>>>(s, cnt, fc_w, fc_b, out);
}

// Round 2
// 406.833 us; speedup vs baseline: 2.6644x; 2.6644x over previous
//
#include <hip/hip_runtime.h>
#include <hip/hip_bf16.h>

#define GRID_ELEMS (8*64*64*64)   // 2,097,152 voxels at level 0
#define H2_VOX     (8*32*32*32)   // 262,144 voxels at level 2
#define H3_VOX     (8*16*16*16)   // 32,768 voxels at level 3

// ---------------------------------------------------------------- scatter
__global__ __launch_bounds__(256) void scatter_k(
    const int* __restrict__ coords, const float* __restrict__ feats,
    float* __restrict__ grid, float* __restrict__ mask, int N)
{
  int i = blockIdx.x * 256 + threadIdx.x;
  if (i >= N) return;
  const int4 c = reinterpret_cast<const int4*>(coords)[i];
  int idx = ((c.x * 64 + c.y) * 64 + c.z) * 64 + c.w;   // b,x,y,z
  atomicAdd(&grid[idx], feats[i]);
  mask[idx] = 1.0f;   // racy same-value store: benign
}

// ------------------------------------------- conv1+relu*mask+conv2+relu*mask2
// Block = 4x4x4 level-2 voxels (8x8x8 level-1 region, 10^3 grid halo tile).
// Phase 0: stage grid+mask tiles in LDS (coalesced; kills the 150x over-fetch).
// Phase 1: lane = l2-voxel, wave-iter = parity child p; h1[32] in regs,
//          W1 via uniform scalar loads; relu*mask -> h1s[p][v2][c] (pitch 33).
// Phase 2: lane = l2-voxel, wave = 16-out-channel group; h1 b32 conflict-free,
//          W2 via SGPR-uniform loads (scalar path, off the LDS port). acc[16].
__global__ __launch_bounds__(256, 2) void fused12_k(
    const float* __restrict__ grid, const float* __restrict__ mask,
    const float* __restrict__ W1, const float* __restrict__ W2,
    float* __restrict__ h2, float* __restrict__ m2out)
{
  __shared__ float gs[1300];          // 10x10x10 tile, idx = x*130+y*13+z
  __shared__ float msk[512];          // [p][v2]
  __shared__ float h1s[8 * 64 * 33];  // [p][v2][c], pitch 33 -> conflict-free

  const int tid = threadIdx.x;
  const int bid = blockIdx.x;
  const int b  = bid >> 9;
  const int X2 = (bid >> 6) & 7, Y2 = (bid >> 3) & 7, Z2 = bid & 7;
  const int gb = b << 18;
  const int gx0 = X2 * 8 - 1, gy0 = Y2 * 8 - 1, gz0 = Z2 * 8 - 1;

  // ---- phase 0: stage tiles
  for (int e = tid; e < 1000; e += 256) {
    const int x = e / 100, r = e - x * 100, y = r / 10, z = r - y * 10;
    const int gx = gx0 + x, gy = gy0 + y, gz = gz0 + z;
    const bool ok = ((unsigned)gx < 64u) & ((unsigned)gy < 64u) & ((unsigned)gz < 64u);
    gs[x * 130 + y * 13 + z] = ok ? grid[gb + (gx << 12) + (gy << 6) + gz] : 0.f;
  }
  for (int e = tid; e < 512; e += 256) {
    const int x1 = e >> 6, y1 = (e >> 3) & 7, z1 = e & 7;
    const float mv = mask[gb + ((X2 * 8 + x1) << 12) + ((Y2 * 8 + y1) << 6) + (Z2 * 8 + z1)];
    const int p  = ((x1 & 1) << 2) | ((y1 & 1) << 1) | (z1 & 1);
    const int v2 = ((x1 >> 1) << 4) | ((y1 >> 1) << 2) | (z1 >> 1);
    msk[p * 64 + v2] = mv;
  }
  __syncthreads();

  const int lane = tid & 63;
  const int wid  = tid >> 6;
  const int x2 = lane >> 4, y2 = (lane >> 2) & 3, z2 = lane & 3;

  // ---- phase 1: conv1 + relu*mask -> h1s
  #pragma unroll 1
  for (int it = 0; it < 2; ++it) {
    const int p  = wid * 2 + it;
    const int lx = 2 * x2 + (p >> 2);
    const int ly = 2 * y2 + ((p >> 1) & 1);
    const int lz = 2 * z2 + (p & 1);
    float h1v[32];
    #pragma unroll
    for (int c = 0; c < 32; ++c) h1v[c] = 0.f;
    #pragma unroll
    for (int tx = 0; tx < 3; ++tx) {
      #pragma unroll
      for (int ty = 0; ty < 3; ++ty) {
        #pragma unroll
        for (int tz = 0; tz < 3; ++tz) {
          const float g = gs[(lx + tx) * 130 + (ly + ty) * 13 + (lz + tz)];
          const float* __restrict__ wp = W1 + ((tx * 3 + ty) * 3 + tz) * 32;  // uniform -> s_load
          #pragma unroll
          for (int c = 0; c < 32; ++c) h1v[c] = fmaf(g, wp[c], h1v[c]);
        }
      }
    }
    const float mk = msk[p * 64 + lane];
    float* hw = &h1s[p * 2112 + lane * 33];
    #pragma unroll
    for (int c = 0; c < 32; ++c) hw[c] = fmaxf(h1v[c], 0.f) * mk;
  }
  __syncthreads();

  // ---- phase 2: conv2 (acc 16 out-channels per thread)
  const int ogrp = __builtin_amdgcn_readfirstlane(wid);   // wave-uniform SGPR
  float acc[16];
  #pragma unroll
  for (int i = 0; i < 16; ++i) acc[i] = 0.f;

  #pragma unroll 1
  for (int p = 0; p < 8; ++p) {
    const float* hbp = &h1s[p * 2112 + lane * 33];
    const float* __restrict__ w2p = W2 + p * 2048 + ogrp * 16;  // uniform base
    #pragma unroll 1
    for (int c4 = 0; c4 < 8; ++c4) {
      const float h0 = hbp[c4 * 4 + 0];
      const float h1 = hbp[c4 * 4 + 1];
      const float h2v = hbp[c4 * 4 + 2];
      const float h3 = hbp[c4 * 4 + 3];
      const float* __restrict__ w0 = w2p + (c4 * 4 + 0) * 64;
      const float* __restrict__ w1 = w2p + (c4 * 4 + 1) * 64;
      const float* __restrict__ w2q = w2p + (c4 * 4 + 2) * 64;
      const float* __restrict__ w3 = w2p + (c4 * 4 + 3) * 64;
      #pragma unroll
      for (int i = 0; i < 16; ++i) {
        acc[i] = fmaf(h0, w0[i], acc[i]);
        acc[i] = fmaf(h1, w1[i], acc[i]);
        acc[i] = fmaf(h2v, w2q[i], acc[i]);
        acc[i] = fmaf(h3, w3[i], acc[i]);
      }
    }
  }

  // m2 = max over children
  float m2v = 0.f;
  #pragma unroll
  for (int p = 0; p < 8; ++p) m2v = fmaxf(m2v, msk[p * 64 + lane]);

  // write h2 = relu(conv2)*m2
  const int vgl = (b << 15) + ((X2 * 4 + x2) << 10) + ((Y2 * 4 + y2) << 5) + (Z2 * 4 + z2);
  float4* hp = reinterpret_cast<float4*>(h2 + ((size_t)vgl << 6) + ogrp * 16);
  #pragma unroll
  for (int i4 = 0; i4 < 4; ++i4) {
    float4 t;
    t.x = fmaxf(acc[i4 * 4 + 0], 0.f) * m2v;
    t.y = fmaxf(acc[i4 * 4 + 1], 0.f) * m2v;
    t.z = fmaxf(acc[i4 * 4 + 2], 0.f) * m2v;
    t.w = fmaxf(acc[i4 * 4 + 3], 0.f) * m2v;
    hp[i4] = t;
  }
  if (wid == 0) m2out[vgl] = m2v;
}

// ------------------------------------- conv3+relu*mask3 + masked global sum
__global__ __launch_bounds__(256) void conv3pool_k(
    const float* __restrict__ h2, const float* __restrict__ m2,
    const float* __restrict__ W3, float* __restrict__ s, float* __restrict__ cnt)
{
  __shared__ float W3s[8 * 64 * 32];   // 64 KB; reused as reduce buffer
  const int tid   = threadIdx.x;
  const int g     = blockIdx.x >> 2;
  const int chunk = blockIdx.x & 3;

  for (int i = tid; i < 8 * 64 * 8; i += 256) {   // float4 granules
    const int pc = i >> 3, o4 = i & 7;
    reinterpret_cast<float4*>(W3s)[i] =
        *reinterpret_cast<const float4*>(&W3[pc * 128 + chunk * 32 + o4 * 4]);
  }
  __syncthreads();

  const int v  = g * 256 + tid;              // [0, 32768)
  const int b  = v >> 12;
  const int x3 = (v >> 8) & 15, y3 = (v >> 4) & 15, z3 = v & 15;
  const int hb = b << 15;

  float acc[32];
  #pragma unroll
  for (int o = 0; o < 32; ++o) acc[o] = 0.f;
  float m3 = 0.f;

  #pragma unroll 1
  for (int p = 0; p < 8; ++p) {
    const int x = 2 * x3 + (p >> 2);
    const int y = 2 * y3 + ((p >> 1) & 1);
    const int z = 2 * z3 + (p & 1);
    const int hv = hb + (x << 10) + (y << 5) + z;
    m3 = fmaxf(m3, m2[hv]);
    const float4* hp4 = reinterpret_cast<const float4*>(h2 + ((size_t)hv << 6));
    #pragma unroll 2
    for (int c4 = 0; c4 < 16; ++c4) {
      const float4 h4 = hp4[c4];
      const float hv4[4] = {h4.x, h4.y, h4.z, h4.w};
      #pragma unroll
      for (int q = 0; q < 4; ++q) {
        const float* w = &W3s[p * 2048 + (c4 * 4 + q) * 32];
        #pragma unroll
        for (int o = 0; o < 32; ++o) acc[o] = fmaf(hv4[q], w[o], acc[o]);
      }
    }
  }

  #pragma unroll
  for (int o = 0; o < 32; ++o) acc[o] = fmaxf(acc[o], 0.f) * m3;

  __syncthreads();
  float* red = W3s;
  #pragma unroll
  for (int o = 0; o < 32; ++o) red[tid * 33 + o] = acc[o];
  red[tid * 33 + 32] = m3;
  __syncthreads();
  if (tid < 33) {
    float sum = 0.f;
    for (int i = 0; i < 256; ++i) sum += red[i * 33 + tid];
    if (tid < 32)            atomicAdd(&s[b * 128 + chunk * 32 + tid], sum);
    else if (chunk == 0)     atomicAdd(&cnt[b], sum);
  }
}

// ---------------------------------------------------------------- final FC
__global__ __launch_bounds__(256) void fc_k(
    const float* __restrict__ s, const float* __restrict__ cnt,
    const float* __restrict__ fc_w, const float* __restrict__ fc_b,
    float* __restrict__ out)
{
  const int b = blockIdx.x, j = threadIdx.x;
  const float inv = 1.f / fmaxf(cnt[b], 1.f);
  float a = fc_b[j];
  #pragma unroll 8
  for (int c = 0; c < 128; ++c) a = fmaf(s[b * 128 + c] * inv, fc_w[c * 256 + j], a);
  out[b * 256 + j] = a;
}

// ---------------------------------------------------------------- launch
extern "C" void kernel_launch(void* const* d_in, const int* in_sizes, int n_in,
                              void* d_out, int out_size, void* d_ws, size_t ws_size,
                              hipStream_t stream)
{
  const int*   coords = (const int*)  d_in[0];
  const float* feats  = (const float*)d_in[1];
  const float* W1     = (const float*)d_in[2];
  const float* W2     = (const float*)d_in[3];
  const float* W3     = (const float*)d_in[4];
  const float* fc_w   = (const float*)d_in[5];
  const float* fc_b   = (const float*)d_in[6];
  float* out = (float*)d_out;
  const int N = in_sizes[0] / 4;

  float* grid = (float*)d_ws;                       //  8.39 MB
  float* mask = grid + GRID_ELEMS;                  //  8.39 MB
  float* h2   = mask + GRID_ELEMS;                  // 67.1  MB
  float* m2   = h2 + (size_t)H2_VOX * 64;           //  1.05 MB
  float* s    = m2 + H2_VOX;                        //  4 KB
  float* cnt  = s + 1024;                           //  32 B

  hipMemsetAsync(grid, 0, (size_t)GRID_ELEMS * 2 * sizeof(float), stream);
  hipMemsetAsync(s,    0, (1024 + 8) * sizeof(float), stream);

  scatter_k  <<<(N + 255) / 256,  256, 0, stream>>>(coords, feats, grid, mask, N);
  fused12_k  <<<H2_VOX / 64,      256, 0, stream>>>(grid, mask, W1, W2, h2, m2);
  conv3pool_k<<<(H3_VOX / 256)*4, 256, 0, stream>>>(h2, m2, W3, s, cnt);
  fc_k       <<<8,                256, 0, stream>>>(s, cnt, fc_w, fc_b, out);
}

// Round 3
// 121.323 us; speedup vs baseline: 8.9345x; 3.3533x over previous
//
#include <hip/hip_runtime.h>
#include <hip/hip_bf16.h>

typedef __attribute__((ext_vector_type(2))) _Float16 f16x2;
typedef __attribute__((ext_vector_type(8))) _Float16 f16x8;
typedef __attribute__((ext_vector_type(4))) float    f32x4;

#define GRID_ELEMS (8*64*64*64)   // 2,097,152 voxels at level 0
#define H2_VOX     (8*32*32*32)   // 262,144 voxels at level 2
#define H3_VOX     (8*16*16*16)   // 32,768 voxels at level 3

// ---------------------------------------------------------------- scatter
__global__ __launch_bounds__(256) void scatter_k(
    const int* __restrict__ coords, const float* __restrict__ feats,
    float* __restrict__ grid, float* __restrict__ mask, int N)
{
  int i = blockIdx.x * 256 + threadIdx.x;
  if (i >= N) return;
  const int4 c = reinterpret_cast<const int4*>(coords)[i];
  int idx = ((c.x * 64 + c.y) * 64 + c.z) * 64 + c.w;   // b,x,y,z
  atomicAdd(&grid[idx], feats[i]);
  mask[idx] = 1.0f;   // racy same-value store: benign
}

// ------------------------------------------------ weight repack (once/launch)
// W2hT[o][k=p*32+c] f16 ; W3hT[o][k=p*64+c] f16 ; W1pk[t] = dup-f16(W1[t])
__global__ __launch_bounds__(256) void setup_k(
    const float* __restrict__ W1, const float* __restrict__ W2, const float* __restrict__ W3,
    _Float16* __restrict__ W2hT, _Float16* __restrict__ W3hT, unsigned* __restrict__ W1pk)
{
  int i = blockIdx.x * 256 + threadIdx.x;
  if (i < 16384) {
    int o = i >> 8, k = i & 255, p = k >> 5, c = k & 31;
    W2hT[i] = (_Float16)W2[p * 2048 + c * 64 + o];
  }
  int j = i - 16384;
  if (j >= 0 && j < 65536) {
    int o = j >> 9, k = j & 511, p = k >> 6, c = k & 63;
    W3hT[j] = (_Float16)W3[p * 8192 + c * 128 + o];
  }
  int t = i - (16384 + 65536);
  if (t >= 0 && t < 864) {
    _Float16 w = (_Float16)W1[t];
    f16x2 v; v.x = w; v.y = w;
    W1pk[t] = __builtin_bit_cast(unsigned, v);
  }
}

// ------------------------------------------- conv1+relu*mask+conv2+relu*mask2
// Block = 4x4x4 l2-voxels. Phase 0: grid tile f16 (even/odd z-pair copies) +
// mask tile. Phase 1: thread = (v2, px/py); pk_fma computes the pz=0/1 voxel
// PAIR at once; h1 f16 stored straight into MFMA B-fragment order in LDS.
// Phase 2: conv2 as MFMA GEMM D[o][v2] = W2hT[o][k] * h1[v2][k], K=256.
__global__ __launch_bounds__(256, 4) void fused12_k(
    const float* __restrict__ grid, const float* __restrict__ mask,
    const unsigned* __restrict__ W1pk, const _Float16* __restrict__ W2hT,
    _Float16* __restrict__ h2, float* __restrict__ m2out)
{
  __shared__ _Float16 gse[100 * 14];       // g(z) at half-index z   (pairs @ even z)
  __shared__ _Float16 gso[100 * 14];       // g(z+1) at half-index z (pairs @ even z)
  __shared__ float    msk[512];            // [p][v2]
  __shared__ float    m2s[64];
  __shared__ _Float16 h1f[4 * 8 * 64 * 8]; // [mt][p][fraglane][8] = B-frag order

  const int tid = threadIdx.x;
  const int bid = blockIdx.x;
  const int b  = bid >> 9;
  const int X2 = (bid >> 6) & 7, Y2 = (bid >> 3) & 7, Z2 = bid & 7;
  const int gb = b << 18;
  const int gx0 = X2 * 8 - 1, gy0 = Y2 * 8 - 1, gz0 = Z2 * 8 - 1;

  // ---- phase 0: stage tiles
  for (int e = tid; e < 1000; e += 256) {
    const int x = e / 100, r = e - x * 100, y = r / 10, z = r - y * 10;
    const int gx = gx0 + x, gy = gy0 + y, gz = gz0 + z;
    const bool ok = ((unsigned)gx < 64u) & ((unsigned)gy < 64u) & ((unsigned)gz < 64u);
    const float v = ok ? grid[gb + (gx << 12) + (gy << 6) + gz] : 0.f;
    const _Float16 h = (_Float16)v;
    const int rowb = (x * 10 + y) * 14;
    gse[rowb + z] = h;
    if (z >= 1) gso[rowb + z - 1] = h;
  }
  for (int e = tid; e < 512; e += 256) {
    const int x1 = e >> 6, y1 = (e >> 3) & 7, z1 = e & 7;
    const float mv = mask[gb + ((X2*8 + x1) << 12) + ((Y2*8 + y1) << 6) + (Z2*8 + z1)];
    const int p  = ((x1 & 1) << 2) | ((y1 & 1) << 1) | (z1 & 1);
    const int v2 = ((x1 >> 1) << 4) | ((y1 >> 1) << 2) | (z1 >> 1);
    msk[p * 64 + v2] = mv;
  }
  __syncthreads();

  const int lane = tid & 63;
  const int wid  = tid >> 6;

  if (wid == 0) {   // m2 = max over children
    float m = 0.f;
    #pragma unroll
    for (int p = 0; p < 8; ++p) m = fmaxf(m, msk[p * 64 + lane]);
    m2s[lane] = m;
    const int x2 = lane >> 4, y2 = (lane >> 2) & 3, z2 = lane & 3;
    m2out[(b << 15) + ((X2*4 + x2) << 10) + ((Y2*4 + y2) << 5) + (Z2*4 + z2)] = m;
  }

  // ---- phase 1: conv1 voxel-pair via pk_fma
  const int v2 = tid & 63;
  const int pq = tid >> 6;                   // pA = 2pq (pz=0), pB = 2pq+1
  {
    const int x2 = v2 >> 4, y2 = (v2 >> 2) & 3, z2 = v2 & 3;
    const int lx = 2*x2 + (pq >> 1), ly = 2*y2 + (pq & 1), lzz = 2*z2;

    f16x2 h1pk[32];
    #pragma unroll
    for (int c = 0; c < 32; ++c) { h1pk[c].x = (_Float16)0; h1pk[c].y = (_Float16)0; }

    #pragma unroll
    for (int tx = 0; tx < 3; ++tx) {
      #pragma unroll
      for (int ty = 0; ty < 3; ++ty) {
        const int rowb = ((lx + tx) * 10 + (ly + ty)) * 14;
        const f16x2 g0 = *reinterpret_cast<const f16x2*>(&gse[rowb + lzz]);
        const f16x2 g1 = *reinterpret_cast<const f16x2*>(&gso[rowb + lzz]);
        const f16x2 g2 = *reinterpret_cast<const f16x2*>(&gse[rowb + lzz + 2]);
        const unsigned* __restrict__ wb = &W1pk[((tx * 3 + ty) * 3) * 32];
        #pragma unroll
        for (int c = 0; c < 32; ++c) {
          h1pk[c] += g0 * __builtin_bit_cast(f16x2, wb[c]);
          h1pk[c] += g1 * __builtin_bit_cast(f16x2, wb[32 + c]);
          h1pk[c] += g2 * __builtin_bit_cast(f16x2, wb[64 + c]);
        }
      }
    }

    const float mA = msk[(2*pq) * 64 + v2], mB = msk[(2*pq + 1) * 64 + v2];
    f16x2 mk; mk.x = (_Float16)mA; mk.y = (_Float16)mB;
    const _Float16 z0 = (_Float16)0;
    #pragma unroll
    for (int c = 0; c < 32; ++c) {
      f16x2 v = h1pk[c];
      v.x = v.x > z0 ? v.x : z0;
      v.y = v.y > z0 ? v.y : z0;
      h1pk[c] = v * mk;
    }

    // store into fragment order: [mt][p][r+16q][j]
    const int mt = v2 >> 4, r = v2 & 15;
    #pragma unroll
    for (int q = 0; q < 4; ++q) {
      f16x8 va, vb;
      #pragma unroll
      for (int j = 0; j < 8; ++j) { va[j] = h1pk[q*8 + j].x; vb[j] = h1pk[q*8 + j].y; }
      const int fl = r + 16 * q;
      *reinterpret_cast<f16x8*>(&h1f[(((mt*8 + 2*pq    ) * 64) + fl) * 8]) = va;
      *reinterpret_cast<f16x8*>(&h1f[(((mt*8 + 2*pq + 1) * 64) + fl) * 8]) = vb;
    }
  }
  __syncthreads();

  // ---- phase 2: conv2 MFMA. wave = o-tile, D[o][v2]
  const int l15 = lane & 15, l4 = lane >> 4;
  f32x4 acc[4];
  #pragma unroll
  for (int nt = 0; nt < 4; ++nt) acc[nt] = (f32x4){0.f, 0.f, 0.f, 0.f};

  const _Float16* __restrict__ w2b = W2hT + ((wid*16 + l15) * 256 + l4 * 8);
  #pragma unroll
  for (int ks = 0; ks < 8; ++ks) {
    const f16x8 af = *reinterpret_cast<const f16x8*>(w2b + ks * 32);
    #pragma unroll
    for (int nt = 0; nt < 4; ++nt) {
      const f16x8 bf = *reinterpret_cast<const f16x8*>(&h1f[((nt*8 + ks) * 64 + lane) * 8]);
      acc[nt] = __builtin_amdgcn_mfma_f32_16x16x32_f16(af, bf, acc[nt], 0, 0, 0);
    }
  }

  // epilogue: relu * m2, cvt f16, store h2[v2][o0..o0+3]
  const int o0 = wid * 16 + l4 * 4;
  #pragma unroll
  for (int nt = 0; nt < 4; ++nt) {
    const int v2l = nt * 16 + l15;
    const float m2v = m2s[v2l];
    const int x2 = v2l >> 4, y2 = (v2l >> 2) & 3, z2 = v2l & 3;
    const int vg = (b << 15) + ((X2*4 + x2) << 10) + ((Y2*4 + y2) << 5) + (Z2*4 + z2);
    const float d0 = fmaxf(acc[nt][0], 0.f) * m2v;
    const float d1 = fmaxf(acc[nt][1], 0.f) * m2v;
    const float d2 = fmaxf(acc[nt][2], 0.f) * m2v;
    const float d3 = fmaxf(acc[nt][3], 0.f) * m2v;
    f16x2 p0; p0.x = (_Float16)d0; p0.y = (_Float16)d1;
    f16x2 p1; p1.x = (_Float16)d2; p1.y = (_Float16)d3;
    uint2 u; u.x = __builtin_bit_cast(unsigned, p0); u.y = __builtin_bit_cast(unsigned, p1);
    reinterpret_cast<uint2*>(h2)[vg * 16 + (o0 >> 2)] = u;
  }
}

// ------------------------------------- conv3 (MFMA) + relu*mask3 + global sum
// Block = 64 l3-voxels. D[o=128][v3=64], K=512. h3 never materialized.
__global__ __launch_bounds__(256, 4) void conv3pool_k(
    const _Float16* __restrict__ h2, const float* __restrict__ m2,
    const _Float16* __restrict__ W3hT, float* __restrict__ s, float* __restrict__ cnt)
{
  __shared__ float m3s[64];
  const int tid = threadIdx.x;
  const int bid = blockIdx.x;
  const int b  = bid >> 6;
  const int X3 = (bid >> 4) & 3, Y3 = (bid >> 2) & 3, Z3 = bid & 3;
  const int lane = tid & 63, wid = tid >> 6;
  const int l15 = lane & 15, l4 = lane >> 4;

  float m3r = 0.f;
  if (tid < 64) {
    const int x3 = X3*4 + (tid >> 4), y3 = Y3*4 + ((tid >> 2) & 3), z3 = Z3*4 + (tid & 3);
    float m = 0.f;
    #pragma unroll
    for (int p = 0; p < 8; ++p) {
      const int x = 2*x3 + (p >> 2), y = 2*y3 + ((p >> 1) & 1), z = 2*z3 + (p & 1);
      m = fmaxf(m, m2[(b << 15) + (x << 10) + (y << 5) + z]);
    }
    m3s[tid] = m;
    m3r = m;
  }
  __syncthreads();

  f32x4 acc[2][4];
  #pragma unroll
  for (int mt = 0; mt < 2; ++mt)
    #pragma unroll
    for (int nt = 0; nt < 4; ++nt) acc[mt][nt] = (f32x4){0.f, 0.f, 0.f, 0.f};

  const int mbase = wid * 32;   // wave covers o in [mbase, mbase+32)
  const _Float16* __restrict__ a0b = W3hT + ((mbase      + l15) * 512 + l4 * 8);
  const _Float16* __restrict__ a1b = W3hT + ((mbase + 16 + l15) * 512 + l4 * 8);

  size_t rowb[4];
  #pragma unroll
  for (int nt = 0; nt < 4; ++nt) {
    const int vloc = nt * 16 + l15;
    const int x3 = X3*4 + (vloc >> 4), y3 = Y3*4 + ((vloc >> 2) & 3), z3 = Z3*4 + (vloc & 3);
    rowb[nt] = ((size_t)((b << 15) + ((2*x3) << 10) + ((2*y3) << 5) + (2*z3))) << 6;
  }

  #pragma unroll
  for (int ss = 0; ss < 16; ++ss) {
    const int p = ss >> 1;
    const int poff = (p >> 2) * 65536 + ((p >> 1) & 1) * 2048 + (p & 1) * 64;
    const int cb = (ss & 1) * 32 + l4 * 8;
    const f16x8 a0 = *reinterpret_cast<const f16x8*>(a0b + ss * 32);
    const f16x8 a1 = *reinterpret_cast<const f16x8*>(a1b + ss * 32);
    #pragma unroll
    for (int nt = 0; nt < 4; ++nt) {
      const f16x8 bf = *reinterpret_cast<const f16x8*>(h2 + rowb[nt] + poff + cb);
      acc[0][nt] = __builtin_amdgcn_mfma_f32_16x16x32_f16(a0, bf, acc[0][nt], 0, 0, 0);
      acc[1][nt] = __builtin_amdgcn_mfma_f32_16x16x32_f16(a1, bf, acc[1][nt], 0, 0, 0);
    }
  }

  // relu * m3, sum over the block's 64 v3, atomic into s[b][o]
  float part[2][4];
  #pragma unroll
  for (int mt = 0; mt < 2; ++mt)
    #pragma unroll
    for (int j = 0; j < 4; ++j) part[mt][j] = 0.f;
  #pragma unroll
  for (int nt = 0; nt < 4; ++nt) {
    const float m3 = m3s[nt * 16 + l15];
    #pragma unroll
    for (int mt = 0; mt < 2; ++mt)
      #pragma unroll
      for (int j = 0; j < 4; ++j)
        part[mt][j] += fmaxf(acc[mt][nt][j], 0.f) * m3;
  }
  #pragma unroll
  for (int d = 1; d < 16; d <<= 1) {
    #pragma unroll
    for (int mt = 0; mt < 2; ++mt)
      #pragma unroll
      for (int j = 0; j < 4; ++j)
        part[mt][j] += __shfl_xor(part[mt][j], d, 64);
  }
  if (l15 == 0) {
    #pragma unroll
    for (int mt = 0; mt < 2; ++mt)
      #pragma unroll
      for (int j = 0; j < 4; ++j)
        atomicAdd(&s[b * 128 + mbase + mt * 16 + l4 * 4 + j], part[mt][j]);
  }
  if (wid == 0) {
    float v = m3r;
    #pragma unroll
    for (int d = 1; d < 64; d <<= 1) v += __shfl_xor(v, d, 64);
    if (lane == 0) atomicAdd(&cnt[b], v);
  }
}

// ---------------------------------------------------------------- final FC
__global__ __launch_bounds__(256) void fc_k(
    const float* __restrict__ s, const float* __restrict__ cnt,
    const float* __restrict__ fc_w, const float* __restrict__ fc_b,
    float* __restrict__ out)
{
  const int b = blockIdx.x, j = threadIdx.x;
  const float inv = 1.f / fmaxf(cnt[b], 1.f);
  float a = fc_b[j];
  #pragma unroll 8
  for (int c = 0; c < 128; ++c) a = fmaf(s[b * 128 + c] * inv, fc_w[c * 256 + j], a);
  out[b * 256 + j] = a;
}

// ---------------------------------------------------------------- launch
extern "C" void kernel_launch(void* const* d_in, const int* in_sizes, int n_in,
                              void* d_out, int out_size, void* d_ws, size_t ws_size,
                              hipStream_t stream)
{
  const int*   coords = (const int*)  d_in[0];
  const float* feats  = (const float*)d_in[1];
  const float* W1     = (const float*)d_in[2];
  const float* W2     = (const float*)d_in[3];
  const float* W3     = (const float*)d_in[4];
  const float* fc_w   = (const float*)d_in[5];
  const float* fc_b   = (const float*)d_in[6];
  float* out = (float*)d_out;
  const int N = in_sizes[0] / 4;

  float*    grid = (float*)d_ws;                 //  8.39 MB
  float*    mask = grid + GRID_ELEMS;            //  8.39 MB
  float*    m2   = mask + GRID_ELEMS;            //  1.05 MB
  float*    s    = m2 + H2_VOX;                  //  4 KB
  float*    cnt  = s + 1024;                     //  32 B
  unsigned* W1pk = (unsigned*)(cnt + 8);         //  3.5 KB
  _Float16* W2hT = (_Float16*)(W1pk + 864);      //  32 KB
  _Float16* W3hT = W2hT + 16384;                 // 128 KB
  _Float16* h2   = W3hT + 65536;                 // 33.5 MB
  // total ws use: ~51.5 MB

  hipMemsetAsync(grid, 0, (size_t)GRID_ELEMS * 2 * sizeof(float), stream);
  hipMemsetAsync(s,    0, 1032 * sizeof(float), stream);

  setup_k    <<<324, 256, 0, stream>>>(W1, W2, W3, W2hT, W3hT, W1pk);
  scatter_k  <<<(N + 255) / 256, 256, 0, stream>>>(coords, feats, grid, mask, N);
  fused12_k  <<<H2_VOX / 64, 256, 0, stream>>>(grid, mask, W1pk, W2hT, h2, m2);
  conv3pool_k<<<H3_VOX / 64, 256, 0, stream>>>(h2, m2, W3hT, s, cnt);
  fc_k       <<<8, 256, 0, stream>>>(s, cnt, fc_w, fc_b, out);
}